// Round 9
// baseline (145.932 us; speedup 1.0000x reference)
//
#include <hip/hip_runtime.h>
#include <math.h>

#define NN 2048
#define BB 4
#define HD 128
#define CNUM 8
#define WPB 4               // waves (= centers) per block in k_dist
#define PCHUNK 64           // nodes per block in k_pool1
#define NCHUNKS (NN / PCHUNK)

typedef unsigned long long u64;

// EXACT branchless top-3 (R7, passed absmax 0.0): key = (bits(sq)<<32)|j.
// sq >= 0 so float bits monotonic; u64 order == exact (sq, j) lexicographic
// == reference tie-break. R8's 11-bit-truncated u32 key caused selection
// swaps between candidates in the same quantum -> absmax 1.4e-3 FAIL.
__device__ __forceinline__ u64 pack_key(float sq, int j) {
    return ((u64)__float_as_uint(sq) << 32) | (unsigned)j;
}
__device__ __forceinline__ void ins3(u64 k, u64& k0, u64& k1, u64& k2) {
    u64 a = k  < k2 ? k  : k2;
    u64 b = k0 > a  ? k0 : a;
    k0    = k0 < a  ? k0 : a;
    k2    = k1 > b  ? k1 : b;
    k1    = k1 < b  ? k1 : b;
}

// K0: pack (x,y,z,|p|^2) once to global (L2-resident, 128 KB total).
__global__ void k_prep(const float* __restrict__ x, float4* __restrict__ pts) {
    const int t = blockIdx.x * 256 + threadIdx.x;   // [0, B*NN)
    const float a = x[3 * t], c = x[3 * t + 1], d = x[3 * t + 2];
    pts[t] = make_float4(a, c, d, a * a + c * c + d * d);
}

// K1: one wave per center, coalesced global loads, exact-key branchless top-3,
// raw v_sqrt_f32, butterfly merge, fused exp/de/dv/ecnt epilogue.
__global__ __launch_bounds__(256) void k_dist(
        const float4* __restrict__ pts,
        int* __restrict__ idx, float* __restrict__ vals,
        float* __restrict__ de, float* __restrict__ dv, int* __restrict__ ecnt) {
    const int b = blockIdx.y;
    const float4* pb = pts + b * NN;
    const int wave = threadIdx.x >> 6;
    const int lane = threadIdx.x & 63;
    const int i = blockIdx.x * WPB + wave;          // this wave's center
    const float4 ci = pb[i];                        // wave-uniform -> broadcast
    u64 k0 = ~0ull, k1 = ~0ull, k2 = ~0ull;
    float dsA = 0.f, dsB = 0.f;
    for (int t = lane; t < NN; t += 256) {          // 8 iterations, 4 elems each
        const float4 pa = pb[t];
        const float4 pv = pb[t + 64];
        const float4 pc = pb[t + 128];
        const float4 pd = pb[t + 192];
        const float qa = fmaxf(ci.w + pa.w - 2.0f * (ci.x * pa.x + ci.y * pa.y + ci.z * pa.z), 0.0f);
        const float qb = fmaxf(ci.w + pv.w - 2.0f * (ci.x * pv.x + ci.y * pv.y + ci.z * pv.z), 0.0f);
        const float qc = fmaxf(ci.w + pc.w - 2.0f * (ci.x * pc.x + ci.y * pc.y + ci.z * pc.z), 0.0f);
        const float qd = fmaxf(ci.w + pd.w - 2.0f * (ci.x * pd.x + ci.y * pd.y + ci.z * pd.z), 0.0f);
        dsA += __builtin_amdgcn_sqrtf(qa + 1e-12f) + __builtin_amdgcn_sqrtf(qc + 1e-12f);
        dsB += __builtin_amdgcn_sqrtf(qb + 1e-12f) + __builtin_amdgcn_sqrtf(qd + 1e-12f);
        ins3(pack_key(qa, t),       k0, k1, k2);
        ins3(pack_key(qb, t + 64),  k0, k1, k2);
        ins3(pack_key(qc, t + 128), k0, k1, k2);
        ins3(pack_key(qd, t + 192), k0, k1, k2);
    }
    float dsum = dsA + dsB;
    // butterfly merge: keys unique (j embedded) -> plain u64 merge
    for (int off = 32; off > 0; off >>= 1) {
        const u64 o0 = __shfl_xor(k0, off);
        const u64 o1 = __shfl_xor(k1, off);
        const u64 o2 = __shfl_xor(k2, off);
        dsum += __shfl_xor(dsum, off);
        ins3(o0, k0, k1, k2);
        ins3(o1, k0, k1, k2);
        ins3(o2, k0, k1, k2);
    }
    if (lane == 0) {
        const float s0 = __uint_as_float((unsigned)(k0 >> 32));
        const float s1 = __uint_as_float((unsigned)(k1 >> 32));
        const float s2 = __uint_as_float((unsigned)(k2 >> 32));
        const int   i0 = (int)(k0 & 0xffffffffu);
        const int   i1 = (int)(k1 & 0xffffffffu);
        const int   i2 = (int)(k2 & 0xffffffffu);
        const float avg = dsum * (1.0f / NN);
        const float inva2 = 1.0f / (avg * avg);
        const float v0 = expf(-s0 * inva2);
        const float v1 = expf(-s1 * inva2);
        const float v2 = expf(-s2 * inva2);
        const int base = (b * NN + i) * 3;
        idx[base] = i0; idx[base + 1] = i1; idx[base + 2] = i2;
        vals[base] = v0; vals[base + 1] = v1; vals[base + 2] = v2;
        de[b * NN + i] = v0 + v1 + v2;
        atomicAdd(&dv[b * NN + i0], v0);
        atomicAdd(&dv[b * NN + i1], v1);
        atomicAdd(&dv[b * NN + i2], v2);
        atomicAdd(&ecnt[b * NN + i0], 1);
        atomicAdd(&ecnt[b * NN + i1], 1);
        atomicAdd(&ecnt[b * NN + i2], 1);
    }
}

// K2: per-batch CSR build (node -> incident edges) + dv2. One block per batch.
// Prefix-sum of ecnt in LDS, then fill with LDS-cursor atomics. Eliminates
// all global f32 atomics from the conv kernels (gather form).
__global__ __launch_bounds__(256) void k_csr(
        const float* __restrict__ dv, const int* __restrict__ ecnt,
        const int* __restrict__ idx, const float* __restrict__ vals,
        float* __restrict__ dv2, int* __restrict__ offs,
        int* __restrict__ inc_e, float* __restrict__ inc_v) {
    __shared__ int part[256];
    __shared__ int cursor[NN];            // 8 KB batch-local cursors
    const int b = blockIdx.x, t = threadIdx.x;
    for (int v = t; v < NN; v += 256) dv2[b * NN + v] = rsqrtf(dv[b * NN + v]);
    // local serial scan of 8 counts per thread
    int c[8];
    const int g0 = b * NN + t * 8;
    int s = 0;
    for (int k = 0; k < 8; ++k) { c[k] = s; s += ecnt[g0 + k]; }
    part[t] = s;
    __syncthreads();
    for (int off = 1; off < 256; off <<= 1) {       // Hillis-Steele inclusive
        const int mine = part[t];
        const int prev = (t >= off) ? part[t - off] : 0;
        __syncthreads();
        part[t] = mine + prev;
        __syncthreads();
    }
    const int base = (t > 0) ? part[t - 1] : 0;     // exclusive prefix
    for (int k = 0; k < 8; ++k) {
        const int loc = base + c[k];
        offs[g0 + k] = b * NN * 3 + loc;
        cursor[t * 8 + k] = loc;
    }
    __syncthreads();
    for (int e = t; e < NN; e += 256) {
        const int ib = (b * NN + e) * 3;
        for (int k = 0; k < 3; ++k) {
            const int j = idx[ib + k];
            const int slot = atomicAdd(&cursor[j], 1);   // LDS atomic
            inc_e[b * NN * 3 + slot] = e;
            inc_v[b * NN * 3 + slot] = vals[ib + k];
        }
    }
}

// K3a: edge gather for conv1: U[e,h] = (1/de)*sum_k val_k*dv2[jk]*W1[jk,h]
__global__ void k_edge1(const float* __restrict__ W1, const int* __restrict__ idx,
                        const float* __restrict__ vals, const float* __restrict__ de,
                        const float* __restrict__ dv2, float* __restrict__ U) {
    const int e = blockIdx.x * 2 + (threadIdx.x >> 7);
    const int b = blockIdx.y, h = threadIdx.x & (HD - 1);
    const int base = (b * NN + e) * 3;
    const int j0 = idx[base], j1 = idx[base + 1], j2 = idx[base + 2];
    const float g0 = vals[base]     * dv2[b * NN + j0];
    const float g1 = vals[base + 1] * dv2[b * NN + j1];
    const float g2 = vals[base + 2] * dv2[b * NN + j2];
    const float ide = 1.0f / de[b * NN + e];
    U[((size_t)(b * NN + e)) * HD + h] =
        ide * (g0 * W1[j0 * HD + h] + g1 * W1[j1 * HD + h] + g2 * W1[j2 * HD + h]);
}

// K3b: node gather: M1[v,h] = dv2[v]*sum_{e inc v} val*U[e,h] + b1[h]
__global__ void k_node1(const float* __restrict__ U, const int* __restrict__ offs,
                        const int* __restrict__ inc_e, const float* __restrict__ inc_v,
                        const float* __restrict__ dv2, const float* __restrict__ b1,
                        float* __restrict__ M1) {
    const int v = blockIdx.x * 2 + (threadIdx.x >> 7);
    const int b = blockIdx.y, h = threadIdx.x & (HD - 1);
    const int g = b * NN + v;
    const int start = offs[g];
    const int end = (v == NN - 1) ? (b + 1) * NN * 3 : offs[g + 1];
    float acc = 0.f;
    for (int s = start; s < end; ++s)
        acc += inc_v[s] * U[((size_t)(b * NN + inc_e[s])) * HD + h];
    M1[(size_t)g * HD + h] = dv2[g] * acc + b1[h];
}

// K4a: edge gather for conv2 (M1 is per-batch)
__global__ void k_edge2(const float* __restrict__ M1, const int* __restrict__ idx,
                        const float* __restrict__ vals, const float* __restrict__ de,
                        const float* __restrict__ dv2, float* __restrict__ U2) {
    const int e = blockIdx.x * 2 + (threadIdx.x >> 7);
    const int b = blockIdx.y, h = threadIdx.x & (HD - 1);
    const int base = (b * NN + e) * 3;
    const int j0 = idx[base], j1 = idx[base + 1], j2 = idx[base + 2];
    const float g0 = vals[base]     * dv2[b * NN + j0];
    const float g1 = vals[base + 1] * dv2[b * NN + j1];
    const float g2 = vals[base + 2] * dv2[b * NN + j2];
    const float ide = 1.0f / de[b * NN + e];
    U2[((size_t)(b * NN + e)) * HD + h] =
        ide * (g0 * M1[((size_t)(b * NN + j0)) * HD + h] +
               g1 * M1[((size_t)(b * NN + j1)) * HD + h] +
               g2 * M1[((size_t)(b * NN + j2)) * HD + h]);
}

// K4b: node gather: F[v,h] = dv2[v]*sum val*U2[e,h]  (final node features)
__global__ void k_node2(const float* __restrict__ U2, const int* __restrict__ offs,
                        const int* __restrict__ inc_e, const float* __restrict__ inc_v,
                        const float* __restrict__ dv2, float* __restrict__ F) {
    const int v = blockIdx.x * 2 + (threadIdx.x >> 7);
    const int b = blockIdx.y, h = threadIdx.x & (HD - 1);
    const int g = b * NN + v;
    const int start = offs[g];
    const int end = (v == NN - 1) ? (b + 1) * NN * 3 : offs[g + 1];
    float acc = 0.f;
    for (int s = start; s < end; ++s)
        acc += inc_v[s] * U2[((size_t)(b * NN + inc_e[s])) * HD + h];
    F[(size_t)g * HD + h] = dv2[g] * acc;
}

// K5a: partial max over 64-node chunks. grid (B, 32) x 128 threads.
__global__ void k_pool1(const float* __restrict__ F, float* __restrict__ pmax) {
    const int b = blockIdx.x, ch = blockIdx.y, h = threadIdx.x;
    const int v0 = ch * PCHUNK;
    float mx = -INFINITY;
    for (int v = v0; v < v0 + PCHUNK; ++v)
        mx = fmaxf(mx, F[((size_t)(b * NN + v)) * HD + h]);
    pmax[(b * NCHUNKS + ch) * HD + h] = mx;
}

// K5b: merge partial maxes + classifier. grid B x 128 threads.
__global__ void k_pool2(const float* __restrict__ Wc, const float* __restrict__ bc,
                        const float* __restrict__ pmax, float* __restrict__ out) {
    __shared__ float smax[HD];
    const int b = blockIdx.x, h = threadIdx.x;
    float mx = -INFINITY;
    for (int c = 0; c < NCHUNKS; ++c)
        mx = fmaxf(mx, pmax[(b * NCHUNKS + c) * HD + h]);
    smax[h] = mx;
    __syncthreads();
    if (h < CNUM) {
        float acc = bc[h];
        for (int q = 0; q < HD; ++q) acc += smax[q] * Wc[q * CNUM + h];
        out[b * CNUM + h] = acc;
    }
}

extern "C" void kernel_launch(void* const* d_in, const int* in_sizes, int n_in,
                              void* d_out, int out_size, void* d_ws, size_t ws_size,
                              hipStream_t stream) {
    const float* x  = (const float*)d_in[0];   // [B,N,3]
    const float* W1 = (const float*)d_in[1];   // [N,H1]
    const float* b1 = (const float*)d_in[2];   // [H1]
    const float* Wc = (const float*)d_in[3];   // [H1,C]
    const float* bc = (const float*)d_in[4];   // [C]
    float* out = (float*)d_out;                // [B,C]

    float* ws = (float*)d_ws;
    float* dv    = ws;                                  // B*N f   (zeroed)
    int*   ecnt  = (int*)(dv + BB * NN);                // B*N i   (zeroed)
    float* de    = (float*)(ecnt + BB * NN);            // B*N f
    float* vals  = de + BB * NN;                        // B*N*3 f
    int*   idx   = (int*)(vals + BB * NN * 3);          // B*N*3 i
    float* dv2   = (float*)(idx + BB * NN * 3);         // B*N f
    int*   offs  = (int*)(dv2 + BB * NN);               // B*N i
    int*   inc_e = offs + BB * NN;                      // B*N*3 i
    float* inc_v = (float*)(inc_e + BB * NN * 3);       // B*N*3 f
    float* U     = inc_v + BB * NN * 3;                 // B*N*HD f (also U2)
    float* M1    = U + (size_t)BB * NN * HD;            // B*N*HD f (also F)
    float* pmax  = M1 + (size_t)BB * NN * HD;           // B*32*HD f
    float4* pts  = (float4*)(pmax + BB * NCHUNKS * HD); // B*N float4

    // zero only [dv | ecnt] (64 KB; Z-buffers are fully overwritten now)
    hipMemsetAsync(dv, 0, (size_t)BB * NN * 2 * sizeof(float), stream);

    k_prep<<<BB * NN / 256, 256, 0, stream>>>(x, pts);
    k_dist<<<dim3(NN / WPB, BB), 256, 0, stream>>>(pts, idx, vals, de, dv, ecnt);
    k_csr<<<BB, 256, 0, stream>>>(dv, ecnt, idx, vals, dv2, offs, inc_e, inc_v);
    k_edge1<<<dim3(NN / 2, BB), 256, 0, stream>>>(W1, idx, vals, de, dv2, U);
    k_node1<<<dim3(NN / 2, BB), 256, 0, stream>>>(U, offs, inc_e, inc_v, dv2, b1, M1);
    k_edge2<<<dim3(NN / 2, BB), 256, 0, stream>>>(M1, idx, vals, de, dv2, U);
    k_node2<<<dim3(NN / 2, BB), 256, 0, stream>>>(U, offs, inc_e, inc_v, dv2, M1);
    k_pool1<<<dim3(BB, NCHUNKS), HD, 0, stream>>>(M1, pmax);
    k_pool2<<<BB, HD, 0, stream>>>(Wc, bc, pmax, out);
}